// Round 3
// 92.366 us; speedup vs baseline: 1.0192x; 1.0192x over previous
//
#include <hip/hip_runtime.h>
#include <math.h>

// Closed form derived from the reference:
//   q[n,0] = prod_{v=1..7} cos(x[n,v]+theta[v])
//   q[n,w] = prod_{v=0..w} cos(x[n,v]+theta[v])   (w = 1..7)
// Attention with E=8, no-max softmax (|score| <= 8/sqrt2), output scramble:
//   final[b,r,k] = sum_c att[b,(r%512)*8+c, r/512] * W[k,c] + bias[k].
//
// R14 == R12 resubmitted (rounds 1-2 benches were infra container failures;
//      full OOB/alignment/barrier audit found no fault or hang hazard).
// R12: PV via mfma_f32_32x32x16_f16 (K=16).  The legacy 32x32x8f16 runs at
//      the same ~8 cyc/CU as the CDNA4 K=16 shape, so contracting 16 t per
//      PV MFMA halves PV issue cycles: per tile 1 QK + 2 PV (24 cyc) instead
//      of 1 QK + 4 PV (40 cyc).  A-frag layout of 32x32x16_f16 is the
//      fp8-sibling contiguous k = 8*hp + j (confirmed by HK m214's
//      permlane32_swap construction, which yields exactly that layout).
//      The K=16 A-frag built by cvt_pkrtz of QK C-regs [8h..8h+7] then has
//      lane-local k->t map = bit2<->bit3 swap of k; instead of
//      permlane-fixing P we store V's t-index bit2<->bit3 swapped in LDS so
//      B agrees with the same permutation, making the B-frag one contiguous
//      ds_read_b128.  VSTR 1028->1032 so every vt row is 16B-aligned
//      (2064 = 129*16) with 4-bank row skew (worst 2-way b128 conflict = free).
// R11: staging prefetch: x(ch+1) loaded into VGPRs right after the staging
//      barrier (in flight across the MFMA loop), cos computed while waiting
//      on the readers-done barrier, only ds_writes between barriers.
//      Structure from R10: TPB=1024 = 4 s-subtiles x 4 t-groups, 2 blocks/CU;
//      32x32 MFMA layout identity (QK C-regs ARE the PV A-frag source).

#define SEQ   4096
#define NB    16
#define SROWS 128          // s-rows per block (4 subtiles x 32)
#define TPB   1024
#define NTG   4            // t-groups
#define TC    1024         // t rows staged per chunk
#define NCH   (SEQ / TC)   // 4 chunks
#define TILES_PER_TG 8     // (TC/32)/NTG
#define KSTR  12           // kf row stride in f16 (24 B)
#define VSTR  1032         // vt row stride in f16 (2064 B: 16B-aligned rows, 4-bank skew)

typedef _Float16 f16x4  __attribute__((ext_vector_type(4)));
typedef _Float16 f16x8  __attribute__((ext_vector_type(8)));
typedef float    f32x16 __attribute__((ext_vector_type(16)));
typedef __fp16   hf2    __attribute__((ext_vector_type(2)));

#if __has_builtin(__builtin_amdgcn_exp2f)
#define EXP2F(x) __builtin_amdgcn_exp2f(x)
#else
#define EXP2F(x) exp2f(x)
#endif

__global__ __launch_bounds__(TPB, 8)   // VGPR cap 64; 2 blocks/CU -> 32 waves/CU
void qattn_kernel(const float* __restrict__ x, const float* __restrict__ theta,
                  const float* __restrict__ wc, const float* __restrict__ bc,
                  float* __restrict__ out)
{
    __shared__ __align__(16) _Float16 kf[TC * KSTR];  // 24576 B: [t][8 f16 + 4 pad]
    __shared__ __align__(16) _Float16 vt[9 * VSTR];   // 18576 B: [w][t-permuted], w=8 = ones
    // after the last MFMA barrier these are re-used:
    float* part = (float*)kf;            // [NTG][SROWS][9] = 18432 B
    float* attn = (float*)vt;            // [SROWS][9]      =  4608 B

    const int tid  = threadIdx.x;
    const int lane = tid & 63;
    const int wv   = tid >> 6;           // 0..15
    const int sub  = wv & 3;             // s-subtile (32 rows)
    const int tg   = wv >> 2;            // t-group
    const int l31  = lane & 31;
    const int hp   = lane >> 5;

    const int b  = blockIdx.x >> 5;
    const int S0 = (blockIdx.x & 31) * SROWS;
    const float* xb = x + (size_t)b * SEQ * 8;

    // t-index bit2<->bit3 swap: matches the K=16 A-frag's natural k->t map
    // (k{0-3}->t{0-3}, k{4-7}->t{8-11}, k{8-11}->t{4-7}, k{12-15}->t{12-15}).
    const int pos = (tid & ~12) | ((tid & 4) << 1) | ((tid & 8) >> 1);

    float th[8];
#pragma unroll
    for (int w = 0; w < 8; ++w) th[w] = theta[w];

    // ones (denominator) row: constant across chunks, write once.
    // max vt row-8 index read is 1023 < 1024, so TPB writes cover it.
    vt[8 * VSTR + tid] = (_Float16)1.0f;

    // ---- Q fragment (B operand of QK): B[k=w=4hp+j][n=s=l31], scaled ----
    f16x4 qfrag;
    {
        const int s = S0 + sub * 32 + l31;
        const float4 xa  = *(const float4*)(xb + s * 8);
        const float4 xb4 = *(const float4*)(xb + s * 8 + 4);
        float c0 = __cosf(xa.x  + th[0]);
        float c1 = __cosf(xa.y  + th[1]);
        float c2 = __cosf(xa.z  + th[2]);
        float c3 = __cosf(xa.w  + th[3]);
        float c4 = __cosf(xb4.x + th[4]);
        float c5 = __cosf(xb4.y + th[5]);
        float c6 = __cosf(xb4.z + th[6]);
        float c7 = __cosf(xb4.w + th[7]);
        float p1 = c0 * c1, p2 = p1 * c2, p3 = p2 * c3, p4 = p3 * c4;
        float p5 = p4 * c5, p6 = p5 * c6, p7 = p6 * c7;
        float p0 = c1 * c2 * c3 * c4 * c5 * c6 * c7;
        const float sc = 0.70710678118654752f * 1.44269504088896341f;
        if (hp == 0)
            qfrag = (f16x4){(_Float16)(p0*sc), (_Float16)(p1*sc),
                            (_Float16)(p2*sc), (_Float16)(p3*sc)};
        else
            qfrag = (f16x4){(_Float16)(p4*sc), (_Float16)(p5*sc),
                            (_Float16)(p6*sc), (_Float16)(p7*sc)};
    }

    f32x16 o = {0.f,0.f,0.f,0.f,0.f,0.f,0.f,0.f,0.f,0.f,0.f,0.f,0.f,0.f,0.f,0.f};

    const int wr = (l31 < 8) ? l31 : 8;  // lanes w>=8 broadcast-read ones row
    const _Float16* kfb = kf + l31 * KSTR + 4 * hp + (tg * TILES_PER_TG) * 32 * KSTR;
    const _Float16* vbb = vt + wr * VSTR + 8 * hp + tg * (TILES_PER_TG * 32);

    // prefetch chunk 0's x rows into registers
    float4 pxa = *(const float4*)(xb + tid * 8);
    float4 pxb = *(const float4*)(xb + tid * 8 + 4);

    for (int ch = 0; ch < NCH; ++ch) {
        // ---- cos/f16 from prefetched regs (overlaps the barrier wait) ----
        float c0 = __cosf(pxa.x + th[0]);
        float c1 = __cosf(pxa.y + th[1]);
        float c2 = __cosf(pxa.z + th[2]);
        float c3 = __cosf(pxa.w + th[3]);
        float c4 = __cosf(pxb.x + th[4]);
        float c5 = __cosf(pxb.y + th[5]);
        float c6 = __cosf(pxb.z + th[6]);
        float c7 = __cosf(pxb.w + th[7]);
        float p1 = c0 * c1, p2 = p1 * c2, p3 = p2 * c3, p4 = p3 * c4;
        float p5 = p4 * c5, p6 = p5 * c6, p7 = p6 * c7;
        float p0 = c1 * c2 * c3 * c4 * c5 * c6 * c7;
        _Float16 h0 = (_Float16)p0, h1 = (_Float16)p1, h2 = (_Float16)p2,
                 h3 = (_Float16)p3, h4 = (_Float16)p4, h5 = (_Float16)p5,
                 h6 = (_Float16)p6, h7 = (_Float16)p7;
        __syncthreads();                  // previous chunk's readers done
        {
            _Float16* krow = kf + tid * KSTR;
            *(f16x4*)(krow)     = (f16x4){h0, h1, h2, h3};
            *(f16x4*)(krow + 4) = (f16x4){h4, h5, h6, h7};
            vt[0 * VSTR + pos] = h0;
            vt[1 * VSTR + pos] = h1;
            vt[2 * VSTR + pos] = h2;
            vt[3 * VSTR + pos] = h3;
            vt[4 * VSTR + pos] = h4;
            vt[5 * VSTR + pos] = h5;
            vt[6 * VSTR + pos] = h6;
            vt[7 * VSTR + pos] = h7;
        }
        __syncthreads();
        // ---- prefetch next chunk's x (in flight across the MFMA loop) ----
        {
            const int nt = ((ch + 1 < NCH) ? (ch + 1) * TC : ch * TC) + tid;
            pxa = *(const float4*)(xb + nt * 8);
            pxb = *(const float4*)(xb + nt * 8 + 4);
        }
        // ---- this wave's 8 t-tiles: QK MFMA -> exp2 -> 2 PV MFMAs (K=16) ----
#pragma unroll 4
        for (int i = 0; i < TILES_PER_TG; ++i) {
            f16x4 kfrag = *(const f16x4*)(kfb + i * 32 * KSTR);
            f32x16 cc = __builtin_amdgcn_mfma_f32_32x32x8f16(
                kfrag, qfrag, (f32x16){0.f,0.f,0.f,0.f,0.f,0.f,0.f,0.f,
                                       0.f,0.f,0.f,0.f,0.f,0.f,0.f,0.f}, 0, 0, 0);
#pragma unroll
            for (int h = 0; h < 2; ++h) {
                union { hf2 q[4]; f16x8 v; } pa;
                pa.q[0] = __builtin_amdgcn_cvt_pkrtz(EXP2F(cc[8*h+0]), EXP2F(cc[8*h+1]));
                pa.q[1] = __builtin_amdgcn_cvt_pkrtz(EXP2F(cc[8*h+2]), EXP2F(cc[8*h+3]));
                pa.q[2] = __builtin_amdgcn_cvt_pkrtz(EXP2F(cc[8*h+4]), EXP2F(cc[8*h+5]));
                pa.q[3] = __builtin_amdgcn_cvt_pkrtz(EXP2F(cc[8*h+6]), EXP2F(cc[8*h+7]));
                // B-frag: contiguous 16B from the permuted vt row (ds_read_b128)
                f16x8 vfrag = *(const f16x8*)(vbb + i * 32 + h * 16);
                o = __builtin_amdgcn_mfma_f32_32x32x16_f16(pa.v, vfrag, o, 0, 0, 0);
            }
        }
    }

    // ---- write per-t-group partials (cols 0..8; col 8 = exp-sum) ----
    __syncthreads();                      // all MFMA reads of kf/vt done; alias now
    if (l31 < 9) {
#pragma unroll
        for (int r = 0; r < 16; ++r) {
            const int sloc = sub * 32 + (r & 3) + 8 * (r >> 2) + 4 * hp;
            part[((tg * SROWS) + sloc) * 9 + l31] = o[r];
        }
    }
    __syncthreads();
    // ---- reduce over t-groups (1152 entries > TPB: strided loop!) ----
    for (int idx = tid; idx < SROWS * 9; idx += TPB) {
        const int rr = idx / 9;
        const int w  = idx - rr * 9;
        float sm = 0.f;
#pragma unroll
        for (int g = 0; g < NTG; ++g) sm += part[((g * SROWS) + rr) * 9 + w];
        attn[rr * 9 + w] = sm;
    }
    __syncthreads();
    if (tid < SROWS * 8) {                // normalize in place (col 8 untouched)
        const int rr = tid >> 3;
        const int w  = tid & 7;
        attn[rr * 9 + w] = attn[rr * 9 + w] / attn[rr * 9 + 8];
    }
    __syncthreads();

    // ---- epilogue: swapaxes/reshape scramble + 8x8 combine ----
    if (tid < SROWS) {
        const int e    = tid >> 4;        // wire
        const int nloc = tid & 15;
        const int r    = e * 512 + (S0 >> 3) + nloc;
        float y[8];
#pragma unroll
        for (int c = 0; c < 8; ++c) y[c] = attn[(nloc * 8 + c) * 9 + e];
        float oo[8];
#pragma unroll
        for (int k = 0; k < 8; ++k) {
            float a = bc[k];
#pragma unroll
            for (int c = 0; c < 8; ++c) a += y[c] * wc[k * 8 + c];
            oo[k] = a;
        }
        float4* op = (float4*)(out + ((size_t)b * SEQ + r) * 8);
        op[0] = make_float4(oo[0], oo[1], oo[2], oo[3]);
        op[1] = make_float4(oo[4], oo[5], oo[6], oo[7]);
    }
}

extern "C" void kernel_launch(void* const* d_in, const int* in_sizes, int n_in,
                              void* d_out, int out_size, void* d_ws, size_t ws_size,
                              hipStream_t stream)
{
    const float* x  = (const float*)d_in[0];
    const float* th = (const float*)d_in[1];
    const float* wc = (const float*)d_in[2];
    const float* bc = (const float*)d_in[3];
    float* out = (float*)d_out;

    qattn_kernel<<<dim3(NB * (SEQ / SROWS)), dim3(TPB), 0, stream>>>(x, th, wc, bc, out);
}

// Round 4
// 88.192 us; speedup vs baseline: 1.0674x; 1.0473x over previous
//
#include <hip/hip_runtime.h>
#include <math.h>

// Closed form derived from the reference:
//   q[n,0] = prod_{v=1..7} cos(x[n,v]+theta[v])
//   q[n,w] = prod_{v=0..w} cos(x[n,v]+theta[v])   (w = 1..7)
// Attention with E=8, no-max softmax (|score| <= 8/sqrt2), output scramble:
//   final[b,r,k] = sum_c att[b,(r%512)*8+c, r/512] * W[k,c] + bias[k].
//
// R15: double-buffered staging.  TC 1024->512, two kf/vt buffers; chunk ch
//      reads buf (ch&1) while waves 0-7 stage chunk ch+1 into the other
//      buffer.  ONE barrier per chunk now separates (reads of buf B in
//      ch-1) from (writes of buf B in ch) and (writes of buf A) from
//      (reads of buf A) -- the cos+ds_write staging section is no longer
//      serialized between two barriers, it overlaps the MFMA/exp2 loop.
//      VSTR=520: rows 1040 B = 65*16 (b128-aligned), 4-bank row skew ->
//      the 8 w-rows of a PV b128 read tile banks 0..31 exactly once.
// R12: PV via mfma_f32_32x32x16_f16 (K=16): per 32x32 tile 1 QK + 2 PV
//      (3x32 SIMD-cyc) instead of 1 QK + 4 PV (5x32).  A-frag k = 8*hp+j
//      (fp8-sibling layout, per HK m214's permlane construction); QK C-regs
//      feed it with k->t = bit2<->bit3 swap, compensated by storing V's
//      t-index bit-swapped in LDS (pos) so the B-frag stays one contiguous
//      ds_read_b128.
// R11: x prefetch into VGPRs one chunk ahead; cos computed from registers.
//      Structure: TPB=1024 = 4 s-subtiles x 4 t-groups, 2 blocks/CU;
//      32x32 MFMA layout identity (QK C-regs ARE the PV A-frag source).

#define SEQ   4096
#define NB    16
#define SROWS 128          // s-rows per block (4 subtiles x 32)
#define TPB   1024
#define NTG   4            // t-groups
#define TC    512          // t rows staged per chunk (per buffer)
#define NCH   (SEQ / TC)   // 8 chunks
#define TPT   4            // tiles per t-group per chunk: (TC/32)/NTG
#define KSTR  12           // kf row stride in f16 (24 B)
#define VSTR  520          // vt row stride in f16 (1040 B = 65*16, 4-bank skew)
#define KFSZ  (TC * KSTR)  // 6144 f16 per buffer
#define VTSZ  (9 * VSTR)   // 4680 f16 per buffer (row 8 = ones)

typedef _Float16 f16x4  __attribute__((ext_vector_type(4)));
typedef _Float16 f16x8  __attribute__((ext_vector_type(8)));
typedef float    f32x16 __attribute__((ext_vector_type(16)));
typedef __fp16   hf2    __attribute__((ext_vector_type(2)));

#if __has_builtin(__builtin_amdgcn_exp2f)
#define EXP2F(x) __builtin_amdgcn_exp2f(x)
#else
#define EXP2F(x) exp2f(x)
#endif

__global__ __launch_bounds__(TPB, 8)   // VGPR cap 64; 2 blocks/CU -> 32 waves/CU
void qattn_kernel(const float* __restrict__ x, const float* __restrict__ theta,
                  const float* __restrict__ wc, const float* __restrict__ bc,
                  float* __restrict__ out)
{
    __shared__ __align__(16) _Float16 kf[2 * KFSZ];  // 24576 B
    __shared__ __align__(16) _Float16 vt[2 * VTSZ];  // 18720 B
    // after the last MFMA barrier these are re-used:
    float* part = (float*)kf;            // [NTG][SROWS][9] = 18432 B <= 24576
    float* attn = (float*)vt;            // [SROWS][9]      =  4608 B <= 18720

    const int tid  = threadIdx.x;
    const int lane = tid & 63;
    const int wv   = tid >> 6;           // 0..15
    const int sub  = wv & 3;             // s-subtile (32 rows)
    const int tg   = wv >> 2;            // t-group
    const int l31  = lane & 31;
    const int hp   = lane >> 5;

    const int b  = blockIdx.x >> 5;
    const int S0 = (blockIdx.x & 31) * SROWS;
    const float* xb = x + (size_t)b * SEQ * 8;

    // t-index bit2<->bit3 swap: matches the K=16 A-frag's natural k->t map
    // (k{0-3}->t{0-3}, k{4-7}->t{8-11}, k{8-11}->t{4-7}, k{12-15}->t{12-15}).
    const int pos = (tid & ~12) | ((tid & 4) << 1) | ((tid & 8) >> 1);

    float th[8];
#pragma unroll
    for (int w = 0; w < 8; ++w) th[w] = theta[w];

    // ---- Q fragment (B operand of QK): B[k=w=4hp+j][n=s=l31], scaled ----
    f16x4 qfrag;
    {
        const int s = S0 + sub * 32 + l31;
        const float4 xa  = *(const float4*)(xb + s * 8);
        const float4 xb4 = *(const float4*)(xb + s * 8 + 4);
        float c0 = __cosf(xa.x  + th[0]);
        float c1 = __cosf(xa.y  + th[1]);
        float c2 = __cosf(xa.z  + th[2]);
        float c3 = __cosf(xa.w  + th[3]);
        float c4 = __cosf(xb4.x + th[4]);
        float c5 = __cosf(xb4.y + th[5]);
        float c6 = __cosf(xb4.z + th[6]);
        float c7 = __cosf(xb4.w + th[7]);
        float p1 = c0 * c1, p2 = p1 * c2, p3 = p2 * c3, p4 = p3 * c4;
        float p5 = p4 * c5, p6 = p5 * c6, p7 = p6 * c7;
        float p0 = c1 * c2 * c3 * c4 * c5 * c6 * c7;
        const float sc = 0.70710678118654752f * 1.44269504088896341f;
        if (hp == 0)
            qfrag = (f16x4){(_Float16)(p0*sc), (_Float16)(p1*sc),
                            (_Float16)(p2*sc), (_Float16)(p3*sc)};
        else
            qfrag = (f16x4){(_Float16)(p4*sc), (_Float16)(p5*sc),
                            (_Float16)(p6*sc), (_Float16)(p7*sc)};
    }

    // staging: waves 0-7, one t-row per thread (cos product chain is per-row)
    auto stage = [&](int buf, float4 xa, float4 xb4) {
        float c0 = __cosf(xa.x  + th[0]);
        float c1 = __cosf(xa.y  + th[1]);
        float c2 = __cosf(xa.z  + th[2]);
        float c3 = __cosf(xa.w  + th[3]);
        float c4 = __cosf(xb4.x + th[4]);
        float c5 = __cosf(xb4.y + th[5]);
        float c6 = __cosf(xb4.z + th[6]);
        float c7 = __cosf(xb4.w + th[7]);
        float p1 = c0 * c1, p2 = p1 * c2, p3 = p2 * c3, p4 = p3 * c4;
        float p5 = p4 * c5, p6 = p5 * c6, p7 = p6 * c7;
        float p0 = c1 * c2 * c3 * c4 * c5 * c6 * c7;
        _Float16 h0 = (_Float16)p0, h1 = (_Float16)p1, h2 = (_Float16)p2,
                 h3 = (_Float16)p3, h4 = (_Float16)p4, h5 = (_Float16)p5,
                 h6 = (_Float16)p6, h7 = (_Float16)p7;
        _Float16* krow = kf + buf * KFSZ + tid * KSTR;
        *(f16x4*)(krow)     = (f16x4){h0, h1, h2, h3};
        *(f16x4*)(krow + 4) = (f16x4){h4, h5, h6, h7};
        _Float16* vb = vt + buf * VTSZ + pos;
        vb[0 * VSTR] = h0;
        vb[1 * VSTR] = h1;
        vb[2 * VSTR] = h2;
        vb[3 * VSTR] = h3;
        vb[4 * VSTR] = h4;
        vb[5 * VSTR] = h5;
        vb[6 * VSTR] = h6;
        vb[7 * VSTR] = h7;
    };

    float4 pxa, pxb;
    if (tid < TC) {
        // ones (denominator) rows: constant, write once per buffer.
        vt[0 * VTSZ + 8 * VSTR + tid] = (_Float16)1.0f;
        vt[1 * VTSZ + 8 * VSTR + tid] = (_Float16)1.0f;
        // stage chunk 0 into buf 0
        const float4 xa  = *(const float4*)(xb + tid * 8);
        const float4 xb4 = *(const float4*)(xb + tid * 8 + 4);
        stage(0, xa, xb4);
        // prefetch chunk 1's x rows
        pxa = *(const float4*)(xb + (TC + tid) * 8);
        pxb = *(const float4*)(xb + (TC + tid) * 8 + 4);
    }

    f32x16 o = {0.f,0.f,0.f,0.f,0.f,0.f,0.f,0.f,0.f,0.f,0.f,0.f,0.f,0.f,0.f,0.f};

    const int wr = (l31 < 8) ? l31 : 8;  // lanes w>=8 broadcast-read ones row
    __syncthreads();                     // buf 0 + ones rows visible

    for (int ch = 0; ch < NCH; ++ch) {
        const int c = ch & 1;
        // ---- stage chunk ch+1 into the other buffer (overlaps MFMA loop) ----
        if (ch + 1 < NCH && tid < TC) {
            stage(c ^ 1, pxa, pxb);
        }
        if (ch + 2 < NCH && tid < TC) {
            pxa = *(const float4*)(xb + ((ch + 2) * TC + tid) * 8);
            pxb = *(const float4*)(xb + ((ch + 2) * TC + tid) * 8 + 4);
        }
        // ---- this wave's 4 t-tiles on buf c: QK -> exp2 -> 2 PV (K=16) ----
        const _Float16* kfb = kf + c * KFSZ + l31 * KSTR + 4 * hp + tg * (TPT * 32) * KSTR;
        const _Float16* vbb = vt + c * VTSZ + wr * VSTR + 8 * hp + tg * (TPT * 32);
#pragma unroll
        for (int i = 0; i < TPT; ++i) {
            f16x4 kfrag = *(const f16x4*)(kfb + i * 32 * KSTR);
            f32x16 cc = __builtin_amdgcn_mfma_f32_32x32x8f16(
                kfrag, qfrag, (f32x16){0.f,0.f,0.f,0.f,0.f,0.f,0.f,0.f,
                                       0.f,0.f,0.f,0.f,0.f,0.f,0.f,0.f}, 0, 0, 0);
#pragma unroll
            for (int h = 0; h < 2; ++h) {
                union { hf2 q[4]; f16x8 v; } pa;
                pa.q[0] = __builtin_amdgcn_cvt_pkrtz(EXP2F(cc[8*h+0]), EXP2F(cc[8*h+1]));
                pa.q[1] = __builtin_amdgcn_cvt_pkrtz(EXP2F(cc[8*h+2]), EXP2F(cc[8*h+3]));
                pa.q[2] = __builtin_amdgcn_cvt_pkrtz(EXP2F(cc[8*h+4]), EXP2F(cc[8*h+5]));
                pa.q[3] = __builtin_amdgcn_cvt_pkrtz(EXP2F(cc[8*h+6]), EXP2F(cc[8*h+7]));
                // B-frag: contiguous 16B from the permuted vt row (ds_read_b128)
                f16x8 vfrag = *(const f16x8*)(vbb + i * 32 + h * 16);
                o = __builtin_amdgcn_mfma_f32_32x32x16_f16(pa.v, vfrag, o, 0, 0, 0);
            }
        }
        __syncthreads();   // reads of buf c done; writes of buf c^1 visible
    }

    // ---- write per-t-group partials (cols 0..8; col 8 = exp-sum) ----
    // (last loop barrier already separates MFMA reads from the alias below)
    if (l31 < 9) {
#pragma unroll
        for (int r = 0; r < 16; ++r) {
            const int sloc = sub * 32 + (r & 3) + 8 * (r >> 2) + 4 * hp;
            part[((tg * SROWS) + sloc) * 9 + l31] = o[r];
        }
    }
    __syncthreads();
    // ---- reduce over t-groups (1152 entries > TPB: strided loop!) ----
    for (int idx = tid; idx < SROWS * 9; idx += TPB) {
        const int rr = idx / 9;
        const int w  = idx - rr * 9;
        float sm = 0.f;
#pragma unroll
        for (int g = 0; g < NTG; ++g) sm += part[((g * SROWS) + rr) * 9 + w];
        attn[rr * 9 + w] = sm;
    }
    __syncthreads();
    if (tid < SROWS * 8) {                // normalize in place (col 8 untouched)
        const int rr = tid >> 3;
        const int w  = tid & 7;
        attn[rr * 9 + w] = attn[rr * 9 + w] / attn[rr * 9 + 8];
    }
    __syncthreads();

    // ---- epilogue: swapaxes/reshape scramble + 8x8 combine ----
    if (tid < SROWS) {
        const int e    = tid >> 4;        // wire
        const int nloc = tid & 15;
        const int r    = e * 512 + (S0 >> 3) + nloc;
        float y[8];
#pragma unroll
        for (int c = 0; c < 8; ++c) y[c] = attn[(nloc * 8 + c) * 9 + e];
        float oo[8];
#pragma unroll
        for (int k = 0; k < 8; ++k) {
            float a = bc[k];
#pragma unroll
            for (int c = 0; c < 8; ++c) a += y[c] * wc[k * 8 + c];
            oo[k] = a;
        }
        float4* op = (float4*)(out + ((size_t)b * SEQ + r) * 8);
        op[0] = make_float4(oo[0], oo[1], oo[2], oo[3]);
        op[1] = make_float4(oo[4], oo[5], oo[6], oo[7]);
    }
}

extern "C" void kernel_launch(void* const* d_in, const int* in_sizes, int n_in,
                              void* d_out, int out_size, void* d_ws, size_t ws_size,
                              hipStream_t stream)
{
    const float* x  = (const float*)d_in[0];
    const float* th = (const float*)d_in[1];
    const float* wc = (const float*)d_in[2];
    const float* bc = (const float*)d_in[3];
    float* out = (float*)d_out;

    qattn_kernel<<<dim3(NB * (SEQ / SROWS)), dim3(TPB), 0, stream>>>(x, th, wc, bc, out);
}